// Round 1
// baseline (1326.075 us; speedup 1.0000x reference)
//
#include <hip/hip_runtime.h>
#include <stdint.h>

typedef __bf16 bf16;
typedef __bf16 bf16x8 __attribute__((ext_vector_type(8)));
typedef __bf16 bf16x4 __attribute__((ext_vector_type(4)));
typedef float  f32x4  __attribute__((ext_vector_type(4)));

__device__ __forceinline__ void async_load16(const void* g, void* l) {
    __builtin_amdgcn_global_load_lds(
        (const __attribute__((address_space(1))) void*)g,
        (__attribute__((address_space(3))) void*)l,
        16, 0, 0);
}

// ---------------- cast fp32 -> bf16, 8 elems/thread ----------------
__global__ __launch_bounds__(256) void cast_f32_bf16(
        const float* __restrict__ s, bf16* __restrict__ d, int n) {
    int i = (blockIdx.x * 256 + threadIdx.x) * 8;
    if (i >= n) return;
    f32x4 v0 = *(const f32x4*)(s + i);
    f32x4 v1 = *(const f32x4*)(s + i + 4);
    bf16x8 o;
    o[0] = (bf16)v0[0]; o[1] = (bf16)v0[1]; o[2] = (bf16)v0[2]; o[3] = (bf16)v0[3];
    o[4] = (bf16)v1[0]; o[5] = (bf16)v1[1]; o[6] = (bf16)v1[2]; o[7] = (bf16)v1[3];
    *(bf16x8*)(d + i) = o;
}

// ---------------- diagnostic fill (ws too small) ----------------
__global__ __launch_bounds__(256) void fill_f32(float* p, float v, int n) {
    int i = blockIdx.x * 256 + threadIdx.x;
    if (i < n) p[i] = v;
}

// ---------------- GEMM (m97 structure) for the small-N layers ----------------
// C[M,N] = A[M,K] * B[N,K]^T (+bias, relu). 128x128 tile, 4 waves 2x2, BK=32.
// Kept for h1/h2 (N=1024): 512 blocks keeps all CUs busy where 256^2 would not.
template<int RELU, int WF32, int WBF16>
__global__ __launch_bounds__(256, 3) void gemm_bt(
        const bf16* __restrict__ A, int lda,
        const bf16* __restrict__ B, int ldb,
        const float* __restrict__ bias,
        float* __restrict__ Cf, int ldcf,
        bf16* __restrict__ Cb, int ldcb,
        int M, int N, int K) {
    (void)M; (void)N;
    __shared__ __attribute__((aligned(16))) bf16 lA[128 * 32];
    __shared__ __attribute__((aligned(16))) bf16 lB[128 * 32];

    const int t = threadIdx.x;
    const int w = t >> 6, lane = t & 63;
    const int wm = w >> 1, wn = w & 1;
    const int m0 = blockIdx.y * 128, n0 = blockIdx.x * 128;
    const int lane15 = lane & 15, quad = lane >> 4;

    f32x4 acc[4][4] = {};

    const int srow = lane >> 2;
    const int scol = (lane & 3) * 8;
    const int c0 = 2 * w, c1 = 2 * w + 1;
    const bf16* gA0 = A + (size_t)(m0 + c0 * 16 + srow) * lda + scol;
    const bf16* gA1 = A + (size_t)(m0 + c1 * 16 + srow) * lda + scol;
    const bf16* gB0 = B + (size_t)(n0 + c0 * 16 + srow) * ldb + scol;
    const bf16* gB1 = B + (size_t)(n0 + c1 * 16 + srow) * ldb + scol;
    bf16* lA0 = &lA[c0 * 512];
    bf16* lA1 = &lA[c1 * 512];
    bf16* lB0 = &lB[c0 * 512];
    bf16* lB1 = &lB[c1 * 512];

    const bf16* fA = &lA[(wm * 64 + lane15) * 32 + quad * 8];
    const bf16* fB = &lB[(wn * 64 + lane15) * 32 + quad * 8];

    for (int k0 = 0; k0 < K; k0 += 32) {
        async_load16(gA0, lA0);
        async_load16(gA1, lA1);
        async_load16(gB0, lB0);
        async_load16(gB1, lB1);
        gA0 += 32; gA1 += 32; gB0 += 32; gB1 += 32;
        __syncthreads();
        bf16x8 a[4], b[4];
#pragma unroll
        for (int i = 0; i < 4; i++) a[i] = *(const bf16x8*)(fA + i * 16 * 32);
#pragma unroll
        for (int j = 0; j < 4; j++) b[j] = *(const bf16x8*)(fB + j * 16 * 32);
#pragma unroll
        for (int i = 0; i < 4; i++)
#pragma unroll
            for (int j = 0; j < 4; j++)
                acc[i][j] = __builtin_amdgcn_mfma_f32_16x16x32_bf16(a[i], b[j], acc[i][j], 0, 0, 0);
        __syncthreads();
    }

#pragma unroll
    for (int i = 0; i < 4; i++) {
        int row = m0 + wm * 64 + i * 16 + quad * 4;
#pragma unroll
        for (int j = 0; j < 4; j++) {
            int col = n0 + wn * 64 + j * 16 + lane15;
            float bv = bias ? bias[col] : 0.0f;
#pragma unroll
            for (int r = 0; r < 4; r++) {
                float v = acc[i][j][r] + bv;
                if (RELU) v = v > 0.0f ? v : 0.0f;
                if (WF32)  Cf[(size_t)(row + r) * ldcf + col] = v;
                if (WBF16) Cb[(size_t)(row + r) * ldcb + col] = (bf16)v;
            }
        }
    }
}

// ---------------- GEMM 256x256, 8-phase schedule (T2+T3+T4+T5) ----------------
// C[M,N] = A[M,K] * B[N,K]^T (+bias). BM=BN=256, BK=64, 512 threads = 8 waves
// (2M x 4N), each wave owns a 128x64 output tile = acc[8][4] 16x16 frags.
// LDS 128 KiB: A[2 buf][256][64] bf16 + B[2 buf][256][64] bf16, linear row-major
// (global_load_lds requires linear dest). Bank-conflict fix (T2) is baked into
// the STAGING global address: 16B chunk col16 is stored at phys col16 ^ (row&7),
// and ds_read applies the same XOR -> every 8 consecutive lanes of a fragment
// read hit all 8 16B windows of a 128B line (conflict-free).
// Schedule per K-tile (4 phases, one C-quadrant x K=64 = 16 MFMA each):
//   ph0: ds_read A(Mq0)+B(Nq0), issue A-stage of tile T+1 | bar | lgkm0 | MFMA | bar
//   ph1: ds_read B(Nq1),        issue B-stage of tile T+1 | bar | lgkm0 | MFMA | bar
//   ph2: ds_read A(Mq1)                                   | bar | lgkm0 | MFMA | bar
//   ph3: MFMA | vmcnt(0) (loads issued 2-3 phases ago -> latency hidden) | bar
// vmcnt never drains at issue point (T4); setprio(1) wraps each MFMA cluster (T5).
template<int RELU, int WF32, int WBF16>
__global__ __launch_bounds__(512, 2) void gemm256(
        const bf16* __restrict__ A, int lda,
        const bf16* __restrict__ B, int ldb,
        const float* __restrict__ bias,
        float* __restrict__ Cf, int ldcf,
        bf16* __restrict__ Cb, int ldcb,
        int K) {
    __shared__ __attribute__((aligned(128))) char sm[131072];

    const int t = threadIdx.x;
    const int w = t >> 6;
    const int lane = t & 63;
    const int wm = w >> 2, wn = w & 3;
    const int l15 = lane & 15, quad = lane >> 4;

    // XCD-bijective swizzle (all grids here have nwg % 8 == 0)
    const int gx = gridDim.x;
    const int nwg = gx * gridDim.y;
    const int orig = blockIdx.y * gx + blockIdx.x;
    const int cpx = nwg >> 3;
    const int wg = (orig & 7) * cpx + (orig >> 3);
    const int m0 = (wg / gx) << 8;
    const int n0 = (wg % gx) << 8;

    f32x4 acc[8][4] = {};

    // ---- staging: thread t, round c covers tile row c*64 + t/8 ----
    // source 16B chunk pre-swizzled: chunk = (t&7) ^ (row&7)  [involution]
    const int srow = t >> 3;                       // 0..63
    const int scol = ((t & 7) ^ (srow & 7)) << 3;  // bf16 elements
    const bf16* gA = A + (size_t)(m0 + srow) * lda + scol;
    const bf16* gB = B + (size_t)(n0 + srow) * ldb + scol;
    char* smA = sm + w * 1024;              // + c*8192 + buf
    char* smB = sm + 65536 + w * 1024;
    const size_t stepA = (size_t)lda << 6;  // 64 rows
    const size_t stepB = (size_t)ldb << 6;

    // ---- fragment read bases: row = <frag row> + l15, chunk = (ks*4+quad)^(row&7)
    // row&7 == l15&7 for all frags (offsets are multiples of 16 rows).
    // ks=1 is chunk XOR 4 -> byte XOR 64 (no carries: low 11 bits < 2048).
    const int swz = (quad ^ (l15 & 7)) << 4;
    const char* aRd0 = sm + ((wm * 128 + l15) << 7) + swz;
    const char* bRd0 = sm + 65536 + ((wn * 64 + l15) << 7) + swz;
    const char* aRd1 = (const char*)((uintptr_t)aRd0 ^ 64);
    const char* bRd1 = (const char*)((uintptr_t)bRd0 ^ 64);

    bf16x8 a[4][2], b[4][2];
    unsigned boff = 0;

#define STAGE_A(nb) do { \
    async_load16(gA,             smA + (nb)); \
    async_load16(gA + stepA,     smA + (nb) + 8192); \
    async_load16(gA + 2 * stepA, smA + (nb) + 16384); \
    async_load16(gA + 3 * stepA, smA + (nb) + 24576); } while (0)
#define STAGE_B(nb) do { \
    async_load16(gB,             smB + (nb)); \
    async_load16(gB + stepB,     smB + (nb) + 8192); \
    async_load16(gB + 2 * stepB, smB + (nb) + 16384); \
    async_load16(gB + 3 * stepB, smB + (nb) + 24576); } while (0)
#define RD_A(Mq) do { _Pragma("unroll") \
    for (int i = 0; i < 4; i++) { \
        a[i][0] = *(const bf16x8*)(aRd0 + boff + (Mq) * 8192 + i * 2048); \
        a[i][1] = *(const bf16x8*)(aRd1 + boff + (Mq) * 8192 + i * 2048); } } while (0)
#define RD_B(Nq) do { _Pragma("unroll") \
    for (int j = 0; j < 2; j++) { \
        b[(Nq) * 2 + j][0] = *(const bf16x8*)(bRd0 + boff + ((Nq) * 2 + j) * 2048); \
        b[(Nq) * 2 + j][1] = *(const bf16x8*)(bRd1 + boff + ((Nq) * 2 + j) * 2048); } } while (0)
#define MMA(Mq, Nq) do { _Pragma("unroll") \
    for (int i = 0; i < 4; i++) { _Pragma("unroll") \
        for (int j = 0; j < 2; j++) { \
            acc[(Mq) * 4 + i][(Nq) * 2 + j] = __builtin_amdgcn_mfma_f32_16x16x32_bf16( \
                a[i][0], b[(Nq) * 2 + j][0], acc[(Mq) * 4 + i][(Nq) * 2 + j], 0, 0, 0); \
            acc[(Mq) * 4 + i][(Nq) * 2 + j] = __builtin_amdgcn_mfma_f32_16x16x32_bf16( \
                a[i][1], b[(Nq) * 2 + j][1], acc[(Mq) * 4 + i][(Nq) * 2 + j], 0, 0, 0); } } } while (0)
#define BAR() __builtin_amdgcn_s_barrier()
#define WAITLGKM() do { \
    asm volatile("s_waitcnt lgkmcnt(0)" ::: "memory"); \
    __builtin_amdgcn_sched_barrier(0); } while (0)

    // prologue: stage tile 0 into buf 0
    STAGE_A(0); STAGE_B(0);
    gA += 64; gB += 64;
    asm volatile("s_waitcnt vmcnt(0)" ::: "memory");
    BAR();

    const int nt = K >> 6;
#define KTILE(PF) do { \
    const unsigned nboff = boff ^ 32768u; \
    /* phase 0: Q(0,0) */ \
    RD_A(0); RD_B(0); \
    if (PF) STAGE_A(nboff); \
    BAR(); WAITLGKM(); \
    __builtin_amdgcn_s_setprio(1); MMA(0, 0); __builtin_amdgcn_s_setprio(0); \
    BAR(); \
    /* phase 1: Q(0,1) */ \
    RD_B(1); \
    if (PF) STAGE_B(nboff); \
    BAR(); WAITLGKM(); \
    __builtin_amdgcn_s_setprio(1); MMA(0, 1); __builtin_amdgcn_s_setprio(0); \
    BAR(); \
    /* phase 2: Q(1,0) */ \
    RD_A(1); \
    BAR(); WAITLGKM(); \
    __builtin_amdgcn_s_setprio(1); MMA(1, 0); __builtin_amdgcn_s_setprio(0); \
    BAR(); \
    /* phase 3: Q(1,1) + drain next-tile stage (issued 2-3 phases ago) */ \
    __builtin_amdgcn_s_setprio(1); MMA(1, 1); __builtin_amdgcn_s_setprio(0); \
    if (PF) { gA += 64; gB += 64; \
        asm volatile("s_waitcnt vmcnt(0)" ::: "memory"); } \
    BAR(); \
    boff = nboff; \
} while (0)

    for (int T = 0; T < nt - 1; ++T) KTILE(1);
    KTILE(0);
#undef KTILE
#undef STAGE_A
#undef STAGE_B
#undef RD_A
#undef RD_B
#undef MMA
#undef BAR
#undef WAITLGKM

    // epilogue: D[row=quad*4+r][col=l15] per 16x16 frag
#pragma unroll
    for (int i = 0; i < 8; i++) {
        int row = m0 + wm * 128 + i * 16 + quad * 4;
#pragma unroll
        for (int j = 0; j < 4; j++) {
            int col = n0 + wn * 64 + j * 16 + l15;
            float bv = bias ? bias[col] : 0.0f;
#pragma unroll
            for (int r = 0; r < 4; r++) {
                float v = acc[i][j][r] + bv;
                if (RELU) v = v > 0.0f ? v : 0.0f;
                if (WF32)  Cf[(size_t)(row + r) * ldcf + col] = v;
                if (WBF16) Cb[(size_t)(row + r) * ldcb + col] = (bf16)v;
            }
        }
    }
}

// ---------------- elementwise combine -> p_pre, q_pre (bf16) ----------------
__global__ __launch_bounds__(256) void combine_pq(
        const bf16* __restrict__ uwb,          // 8192 x 4096 bf16 (u | w)
        const bf16* __restrict__ GBu, const bf16* __restrict__ GBw,
        const float* __restrict__ bias_p, const float* __restrict__ bias_q,
        bf16* __restrict__ pp, bf16* __restrict__ qp) {
    int idx = (blockIdx.x * 256 + threadIdx.x) * 4;   // into 8192x2048
    int row = idx >> 11;
    int col = idx & 2047;
    size_t base = (size_t)row * 4096 + col;
    bf16x4 u4  = *(const bf16x4*)(uwb + base);
    bf16x4 w4  = *(const bf16x4*)(uwb + base + 2048);
    bf16x4 gu4 = *(const bf16x4*)(GBu + base);
    bf16x4 bu4 = *(const bf16x4*)(GBu + base + 2048);
    bf16x4 gw4 = *(const bf16x4*)(GBw + base);
    bf16x4 bw4 = *(const bf16x4*)(GBw + base + 2048);
    bf16x4 po, qo;
#pragma unroll
    for (int r = 0; r < 4; r++) {
        float u = (float)u4[r], w = (float)w4[r];
        float gu = (float)gu4[r], gw = (float)gw4[r];
        float bu = (float)bu4[r], bw = (float)bw4[r];
        float p = u * gu + w * gw + w * bu - u * bw + bias_p[col + r];
        float q = w * gu - u * gw - u * bu - w * bw + bias_q[col + r];
        po[r] = (bf16)p;
        qo[r] = (bf16)q;
    }
    *(bf16x4*)(pp + idx) = po;
    *(bf16x4*)(qp + idx) = qo;
}

extern "C" void kernel_launch(void* const* d_in, const int* in_sizes, int n_in,
                              void* d_out, int out_size, void* d_ws, size_t ws_size,
                              hipStream_t stream) {
    (void)in_sizes; (void)n_in;
    const int BT = 8192, NX = 4096, NR = 1024, NB = 2048;

    const float* x      = (const float*)d_in[0];
    const float* W_h    = (const float*)d_in[1];
    const float* b_h    = (const float*)d_in[2];
    const float* W_h2   = (const float*)d_in[3];
    const float* b_h2   = (const float*)d_in[4];
    const float* W_y    = (const float*)d_in[5];
    const float* b_y    = (const float*)d_in[6];
    const float* G      = (const float*)d_in[7];
    const float* Bm     = (const float*)d_in[8];
    const float* bias_p = (const float*)d_in[9];
    const float* bias_q = (const float*)d_in[10];
    const float* W_p    = (const float*)d_in[11];
    const float* b_p    = (const float*)d_in[12];
    const float* W_q    = (const float*)d_in[13];
    const float* b_q    = (const float*)d_in[14];
    float* out = (float*)d_out;

    // ---- workspace layout (bytes), lifetime-based aliasing ----
    const size_t NEED = 320864256ull;  // ~321 MB
    if (ws_size < NEED) {  // diagnostic: report available MB via d_out
        fill_f32<<<dim3((out_size + 255) / 256), dim3(256), 0, stream>>>(
            out, (float)(ws_size >> 20), out_size);
        return;
    }
    char* ws = (char*)d_ws;
    bf16* xb   = (bf16*)(ws + 0);            // 67.1 MB, dead after h1 GEMM
    bf16* GBu  = (bf16*)(ws + 0);            // 67.1 MB (overlays xb)
    bf16* uwb  = (bf16*)(ws + 67108864);     // 67.1 MB, live through combine
    bf16* GBw  = (bf16*)(ws + 134217728);    // 67.1 MB
    bf16* h1   = (bf16*)(ws + 201326592);    // 16.8 MB, dead after h2 GEMM
    bf16* pp   = (bf16*)(ws + 201326592);    // 33.6 MB (overlays h1+h2, both dead)
    bf16* h2   = (bf16*)(ws + 218103808);    // 16.8 MB, dead after uw GEMM
    bf16* qp   = (bf16*)(ws + 234881024);    // 33.6 MB
    bf16* whb  = (bf16*)(ws + 268435456);    // 8.4 MB
    bf16* wh2b = (bf16*)(ws + 276824064);    // 2.1 MB
    bf16* wyb  = (bf16*)(ws + 278921216);    // 8.4 MB
    bf16* gbm  = (bf16*)(ws + 287309824);    // 16.8 MB: [G; Bm] stacked (4096 x 2048)
    bf16* wpb  = (bf16*)(ws + 304087040);    // 8.4 MB
    bf16* wqb  = (bf16*)(ws + 312475648);    // 8.4 MB

    dim3 blk(256);
    auto cast = [&](const float* s, bf16* d, int n) {
        cast_f32_bf16<<<dim3((n / 8 + 255) / 256), blk, 0, stream>>>(s, d, n);
    };
    cast(x,    xb,   BT * NX);
    cast(W_h,  whb,  NR * NX);
    cast(W_h2, wh2b, NR * NR);
    cast(W_y,  wyb,  NX * NR);
    cast(G,    gbm,            NB * NB);   // rows 0..2047 of stacked weight
    cast(Bm,   gbm + (size_t)NB * NB, NB * NB);   // rows 2048..4095
    cast(W_p,  wpb,  NB * NB);
    cast(W_q,  wqb,  NB * NB);

    // h1 = relu(x @ W_h^T + b_h)            [8192,1024,K=4096] (N=1024 -> 128^2 kernel)
    gemm_bt<1, 0, 1><<<dim3(NR / 128, BT / 128), blk, 0, stream>>>(
        xb, NX, whb, NX, b_h, nullptr, 0, h1, NR, BT, NR, NX);
    // h2 = relu(h1 @ W_h2^T + b_h2)         [8192,1024,K=1024]
    gemm_bt<1, 0, 1><<<dim3(NR / 128, BT / 128), blk, 0, stream>>>(
        h1, NR, wh2b, NR, b_h2, nullptr, 0, h2, NR, BT, NR, NR);

    // ---- big GEMMs on the 256^2 8-phase kernel ----
    // uw = h2 @ W_y^T + b_y                 [8192,4096,K=1024] -> fp32 d_out + bf16 ws
    gemm256<0, 1, 1><<<dim3(NX / 256, BT / 256), dim3(512), 0, stream>>>(
        h2, NR, wyb, NR, b_y, out, NX, uwb, NX, NR);
    // GBu = u @ [G;Bm]^T, GBw = w @ [G;Bm]^T   [8192,4096,K=2048] each
    gemm256<0, 0, 1><<<dim3(NX / 256, BT / 256), dim3(512), 0, stream>>>(
        uwb,      NX, gbm, NB, nullptr, nullptr, 0, GBu, NX, NB);
    gemm256<0, 0, 1><<<dim3(NX / 256, BT / 256), dim3(512), 0, stream>>>(
        uwb + NB, NX, gbm, NB, nullptr, nullptr, 0, GBw, NX, NB);
    // elementwise combine -> p_pre, q_pre (bf16)
    combine_pq<<<dim3(BT * NB / 4 / 256), blk, 0, stream>>>(
        uwb, GBu, GBw, bias_p, bias_q, pp, qp);
    // p = p_pre @ W_p^T + b_p -> d_out[33554432..]
    gemm256<0, 1, 0><<<dim3(NB / 256, BT / 256), dim3(512), 0, stream>>>(
        pp, NB, wpb, NB, b_p, out + (size_t)BT * NX, NB, nullptr, 0, NB);
    // q = q_pre @ W_q^T + b_q -> d_out[50331648..]
    gemm256<0, 1, 0><<<dim3(NB / 256, BT / 256), dim3(512), 0, stream>>>(
        qp, NB, wqb, NB, b_q, out + (size_t)BT * NX + (size_t)BT * NB, NB, nullptr, 0, NB);
}